// Round 10
// baseline (6723.406 us; speedup 1.0000x reference)
//
#include <hip/hip_runtime.h>

// NeuralMemory scan: B=4, S=256, H=128, EXP=2, DEPTH=2.
// Round 20: R17 base (verified 1645us scan) + per-wave publish.
// R18/R19 post-mortem: BOTH L2-shortcut attempts falsified by counters
// (R18: sc1 stores don't refresh local L2 -> stale lines; R19: no-sc1
// atomics still execute memory-side -> WRITE_SIZE 2x). The IF$ RT is
// structural. So attack what surrounds the RT: each publish sat behind
// a cross-wave LDS combine + barrier (~0.25us) and 3 of 6 barriers only
// served those combines. Now: waves publish their OWN partials (8/pos)
// immediately after the intra-wave shfl; consumers combine 32 tagged
// values (4WG x 8wave, 64B-contiguous per (wg,pos)) INSIDE the RT
// window via thread pairs: primary loads 2 WGs (8x dwordx4 sc0 sc1, one
// vmcnt), partner loads other 2 and hands over through an LDS tag spin
// (no barrier). Barriers 6 -> 3 per step. Biases applied consumer-side
// (b2 arrays full-width per WG, locally updated). Slots 640KB. The
// visibility path stays R17's proven agent-store -> device-load; no
// cache-locality assumptions; tag spins + retry fallbacks throughout.
// Predicted: scan -> ~1430-1530; >=1700 falsifies (revert to R17 floor).

constexpr int HD  = 128;   // H
constexpr int SEQ = 256;   // S
constexpr int NB  = 4;     // B
constexpr int ED  = 256;   // H*EXP
constexpr int CW  = 64;    // hidden units per WG per layer (ED/NWG)
constexpr int NWG = 4;     // workgroups per batch
constexpr int TOK = 8;     // tokens per qkv block
// slot region per batch (ull units): B 4*128*8=4096, t1 4*256*8=8192, t2 8192
constexpr int BATSLOT = 20480;

typedef unsigned long long ull;
typedef unsigned int v4u __attribute__((ext_vector_type(4)));

// fast sigmoid: v_exp_f32 computes 2^x, so 1/(1+e^-x) = rcp(1 + 2^(-x*log2e)).
__device__ __forceinline__ float sigm(float x){
  float e;
  asm("v_exp_f32 %0, %1" : "=v"(e) : "v"(x * -1.44269504088896f));
  float r;
  asm("v_rcp_f32 %0, %1" : "=v"(r) : "v"(1.0f + e));
  return r;
}

template<int CTRL>
__device__ __forceinline__ float dpp_add(float x){
  int y = __builtin_amdgcn_update_dpp(0, __float_as_int(x), CTRL, 0xF, 0xF, true);
  return x + __int_as_float(y);
}
__device__ __forceinline__ float red32(float x){
  x = dpp_add<0xB1>(x);
  x = dpp_add<0x4E>(x);
  x = dpp_add<0x141>(x);
  x = dpp_add<0x140>(x);
  x += __int_as_float(__builtin_amdgcn_ds_swizzle(__float_as_int(x), 0x401F));
  return x;
}
__device__ __forceinline__ float red64(float x){
  x = red32(x);
  x += __shfl_xor(x, 32, 64);
  return x;
}

// Sum 16 tagged slots from two 64B chunks (8 ull each), device-coherent
// loads, all 8 dwordx4 in flight at once (one vmcnt). Slot = {seq:32|val:32};
// in each dwordx4: .x=val0 .y=tag0 .z=val1 .w=tag1. Retries fall back to
// individual agent atomic loads.
__device__ __forceinline__ float sum16(const ull* a, const ull* b, unsigned seq){
  v4u r0,r1,r2,r3,r4,r5,r6,r7;
  asm volatile(
    "global_load_dwordx4 %0, %8, off sc0 sc1\n\t"
    "global_load_dwordx4 %1, %9, off sc0 sc1\n\t"
    "global_load_dwordx4 %2, %10, off sc0 sc1\n\t"
    "global_load_dwordx4 %3, %11, off sc0 sc1\n\t"
    "global_load_dwordx4 %4, %12, off sc0 sc1\n\t"
    "global_load_dwordx4 %5, %13, off sc0 sc1\n\t"
    "global_load_dwordx4 %6, %14, off sc0 sc1\n\t"
    "global_load_dwordx4 %7, %15, off sc0 sc1\n\t"
    "s_waitcnt vmcnt(0)"
    : "=&v"(r0),"=&v"(r1),"=&v"(r2),"=&v"(r3),
      "=&v"(r4),"=&v"(r5),"=&v"(r6),"=&v"(r7)
    : "v"(a),"v"(a+2),"v"(a+4),"v"(a+6),
      "v"(b),"v"(b+2),"v"(b+4),"v"(b+6)
    : "memory");
  float s = 0.f; unsigned got = 0;
  v4u rr[8] = {r0,r1,r2,r3,r4,r5,r6,r7};
  #pragma unroll
  for (int i=0;i<8;i++){
    if (rr[i].y==seq){ s += __uint_as_float(rr[i].x); got |= 1u<<(2*i); }
    if (rr[i].w==seq){ s += __uint_as_float(rr[i].z); got |= 1u<<(2*i+1); }
  }
  while (got != 0xFFFFu){
    #pragma unroll
    for (int i=0;i<16;i++){
      if (!(got & (1u<<i))){
        const ull* p = (i<8) ? (a+i) : (b+(i-8));
        ull v = __hip_atomic_load(p, __ATOMIC_RELAXED, __HIP_MEMORY_SCOPE_AGENT);
        if ((unsigned)(v>>32)==seq){ s += __uint_as_float((unsigned)v); got |= 1u<<i; }
      }
    }
  }
  return s;
}

// ---------------- kernel 1: q/k/v + gate scalars (8 tokens/block) ----------------
__global__ __launch_bounds__(128) void qkv_kernel(
    const float* __restrict__ x,
    const float* __restrict__ Wq, const float* __restrict__ Wk, const float* __restrict__ Wv,
    const float* __restrict__ w_lr, const float* __restrict__ b_lr,
    const float* __restrict__ w_fg, const float* __restrict__ b_fg,
    const float* __restrict__ w_mo, const float* __restrict__ b_mo,
    float* __restrict__ qb, float* __restrict__ kb, float* __restrict__ vb,
    float* __restrict__ thb, float* __restrict__ alb, float* __restrict__ etb)
{
  const int t0 = blockIdx.x * TOK;
  const int o  = threadIdx.x;
  __shared__ float xl[TOK][HD];
  __shared__ float red2[2][8];

  #pragma unroll
  for (int tt=0; tt<TOK; ++tt)
    xl[tt][o] = x[(size_t)(t0+tt)*HD + o];
  const float wl = w_lr[o], wf = w_fg[o], wm = w_mo[o];
  const float blr = b_lr[0], bfg = b_fg[0], bmo = b_mo[0];
  __syncthreads();

  float aq[TOK], ak[TOK], av[TOK];
  #pragma unroll
  for (int tt=0; tt<TOK; ++tt){ aq[tt]=0.f; ak[tt]=0.f; av[tt]=0.f; }
  for (int i=0; i<HD; i+=4){
    float wq0=Wq[(i+0)*HD+o], wk0=Wk[(i+0)*HD+o], wv0=Wv[(i+0)*HD+o];
    float wq1=Wq[(i+1)*HD+o], wk1=Wk[(i+1)*HD+o], wv1=Wv[(i+1)*HD+o];
    float wq2=Wq[(i+2)*HD+o], wk2=Wk[(i+2)*HD+o], wv2=Wv[(i+2)*HD+o];
    float wq3=Wq[(i+3)*HD+o], wk3=Wk[(i+3)*HD+o], wv3=Wv[(i+3)*HD+o];
    #pragma unroll
    for (int tt=0; tt<TOK; ++tt){
      float4 xv = *reinterpret_cast<const float4*>(&xl[tt][i]);
      aq[tt]=fmaf(xv.x,wq0,aq[tt]); ak[tt]=fmaf(xv.x,wk0,ak[tt]); av[tt]=fmaf(xv.x,wv0,av[tt]);
      aq[tt]=fmaf(xv.y,wq1,aq[tt]); ak[tt]=fmaf(xv.y,wk1,ak[tt]); av[tt]=fmaf(xv.y,wv1,av[tt]);
      aq[tt]=fmaf(xv.z,wq2,aq[tt]); ak[tt]=fmaf(xv.z,wk2,ak[tt]); av[tt]=fmaf(xv.z,wv2,av[tt]);
      aq[tt]=fmaf(xv.w,wq3,aq[tt]); ak[tt]=fmaf(xv.w,wk3,ak[tt]); av[tt]=fmaf(xv.w,wv3,av[tt]);
    }
  }
  #pragma unroll
  for (int tt=0; tt<TOK; ++tt){
    const size_t idx = (size_t)(t0+tt);
    float a_q=aq[tt], a_k=ak[tt], a_v=av[tt];
    float sq_ = a_q*sigm(a_q);
    float sk_ = a_k*sigm(a_k);
    float sv_ = a_v*sigm(a_v);
    float xo = xl[tt][o];
    float p0 = red64(sq_*sq_);
    float p1 = red64(sk_*sk_);
    float p2 = red64(xo*wl);
    float p3 = red64(xo*wf);
    float p4 = red64(xo*wm);
    if ((o&63)==0){
      int w = o>>6;
      red2[w][0]=p0; red2[w][1]=p1; red2[w][2]=p2; red2[w][3]=p3; red2[w][4]=p4;
    }
    __syncthreads();
    float nq = red2[0][0]+red2[1][0];
    float nk = red2[0][1]+red2[1][1];
    qb[idx*HD+o] = sq_ / fmaxf(sqrtf(nq), 1e-12f);
    kb[idx*HD+o] = sk_ / fmaxf(sqrtf(nk), 1e-12f);
    vb[idx*HD+o] = sv_;
    if (o==0){
      float dl = red2[0][2]+red2[1][2];
      float df = red2[0][3]+red2[1][3];
      float dm = red2[0][4]+red2[1][4];
      thb[idx] = sigm(dl + blr) * 0.01f;
      alb[idx] = sigm(df + bfg);
      etb[idx] = sigm(dm + bmo);
    }
    __syncthreads();
  }
}

// ---------------- kernel 2: the sequential scan ----------------
__global__ __launch_bounds__(512, 1) void scan_kernel(
    const float* __restrict__ w1_0g, const float* __restrict__ b1_0g,
    const float* __restrict__ w2_0g, const float* __restrict__ b2_0g,
    const float* __restrict__ mw1_0g, const float* __restrict__ mb1_0g,
    const float* __restrict__ mw2_0g, const float* __restrict__ mb2_0g,
    const float* __restrict__ w1_1g, const float* __restrict__ b1_1g,
    const float* __restrict__ w2_1g, const float* __restrict__ b2_1g,
    const float* __restrict__ mw1_1g, const float* __restrict__ mb1_1g,
    const float* __restrict__ mw2_1g, const float* __restrict__ mb2_1g,
    const float* __restrict__ qbuf, const float* __restrict__ kbuf, const float* __restrict__ vbuf,
    const float* __restrict__ thb, const float* __restrict__ alb, const float* __restrict__ etb,
    ull* __restrict__ red, float* __restrict__ out)
{
  // XCD co-location (R17-verified): XCD = blockIdx % 8; 32 blocks, keep (rb&7)<NB.
  const int rb  = blockIdx.x;
  const int b   = rb & 7;
  if (b >= NB) return;
  const int wg  = rb >> 3;
  const int tid = threadIdx.x;
  const int iG  = tid & 31;
  const int jG  = tid >> 5;
  const int i0  = iG*4;
  const int j0  = jG*4;
  const int c0  = wg*CW;
  const int wv  = tid >> 6;     // wave id 0..7

  ull* SB = red + (size_t)b*BATSLOT;
  // slot addr: [wg][pos][wave], 8 contiguous per (wg,pos) = 64B aligned
  auto sB = [&](int w_,int pos){ return SB + (((w_<<7)+pos)<<3); };            // 4*128*8
  auto s1 = [&](int w_,int pos){ return SB + 4096  + (((w_<<8)+pos)<<3); };    // 4*256*8
  auto s2 = [&](int w_,int pos){ return SB + 12288 + (((w_<<8)+pos)<<3); };

  __shared__ float pw1L[2][16][512];   // 64 KB p0 (w1)
  __shared__ float pw2L[2][16][512];   // 64 KB p0 (w2)
  __shared__ float h1k[HD], h1q[HD], h2k[HD], gh1[HD];
  __shared__ float b1p[2][CW], b1n[2][CW];
  __shared__ float b2p0f[HD], b2n0f[HD], b2p1f[HD], b2n1f[HD];   // FULL width
  __shared__ unsigned pcT1[256], pcV1[256], pcT2[256], pcV2[256], pcTB[128], pcVB[128];

  float nw1[2][16], nw2[2][16];
  {
    const float* w1s[2]  = {w1_0g,  w1_1g};
    const float* mw1s[2] = {mw1_0g, mw1_1g};
    const float* w2s[2]  = {w2_0g,  w2_1g};
    const float* mw2s[2] = {mw2_0g, mw2_1g};
    #pragma unroll
    for (int l=0;l<2;l++){
      #pragma unroll
      for (int jj=0;jj<4;jj++){
        #pragma unroll
        for (int ii=0;ii<4;ii++){
          int gi1 = (i0+ii)*ED + (c0+j0+jj);
          float p1 = w1s[l][gi1];
          pw1L[l][jj*4+ii][tid] = p1;
          nw1[l][jj*4+ii] = p1 + mw1s[l][gi1];
          int gi2 = (c0+j0+jj)*HD + (i0+ii);
          float p2 = w2s[l][gi2];
          pw2L[l][jj*4+ii][tid] = p2;
          nw2[l][jj*4+ii] = p2 + mw2s[l][gi2];
        }
      }
    }
  }
  if (tid < CW){
    float p0a = b1_0g[c0+tid], p1a = b1_1g[c0+tid];
    b1p[0][tid] = p0a; b1n[0][tid] = p0a + mb1_0g[c0+tid];
    b1p[1][tid] = p1a; b1n[1][tid] = p1a + mb1_1g[c0+tid];
  }
  if (tid < 128){
    float pa0 = b2_0g[tid], pa1 = b2_1g[tid];
    b2p0f[tid] = pa0; b2n0f[tid] = pa0 + mb2_0g[tid];
    b2p1f[tid] = pa1; b2n1f[tid] = pa1 + mb2_1g[tid];
    pcTB[tid] = 0;
  }
  if (tid < 256){ pcT1[tid] = 0; pcT2[tid] = 0; }

  auto pub = [&](ull* slot, unsigned seq, float val){
    __hip_atomic_store(slot, ((ull)seq<<32) | (ull)__float_as_uint(val),
                       __ATOMIC_RELAXED, __HIP_MEMORY_SCOPE_AGENT);
  };

  volatile unsigned* vT1 = pcT1; volatile unsigned* vV1 = pcV1;
  volatile unsigned* vT2 = pcT2; volatile unsigned* vV2 = pcV2;
  volatile unsigned* vTB = pcTB; volatile unsigned* vVB = pcVB;

  // loop-carried per-thread state
  float u1_r[4], s1_r[4], sg1_r[4], u2_r[4], s2_r[4], sg2_r[4], h1k_r[4], v_r[4], vc_r = 0.f;
  float kprev4[4];

  // forward from layer-0 preacts. ro: tid<128 -> q_t[tid]; [128,256) -> k_{t+1}[tid-128].
  auto fwd = [&](int t, bool writeOut, unsigned seq,
                 const float* uq, const float* uk, float ro){
    float sq1q[4];
    #pragma unroll
    for (int jj=0;jj<4;jj++){
      float vq = uq[jj], vk = uk[jj];
      u1_r[jj]=vk;
      float sgk = sigm(vk);
      sg1_r[jj]=sgk; s1_r[jj]=vk*sgk;
      sq1q[jj]=vq*sigm(vq);
    }
    // layer0 out partials
    float oq[4]={0,0,0,0}, ok[4]={0,0,0,0};
    #pragma unroll
    for (int jj=0;jj<4;jj++){
      #pragma unroll
      for (int oo=0;oo<4;oo++){
        float w = nw2[0][jj*4+oo];
        oq[oo] = fmaf(sq1q[jj], w, oq[oo]);
        ok[oo] = fmaf(s1_r[jj], w, ok[oo]);
      }
    }
    #pragma unroll
    for (int oo=0;oo<4;oo++){
      oq[oo] += __shfl_xor(oq[oo], 32, 64);
      ok[oo] += __shfl_xor(ok[oo], 32, 64);
    }
    // PUBLISH type1 per-wave, immediately (no barrier, no LDS combine)
    if (!(tid & 32)){
      #pragma unroll
      for (int oo=0;oo<4;oo++){
        pub(s1(wg, i0+oo)     + wv, seq, oq[oo]);
        pub(s1(wg, 128+i0+oo) + wv, seq, ok[oo]);
      }
    }
    // CONSUME type1 via thread pairs (32 slots/pos; primary 2 WGs + pair 2 WGs)
    if (tid < 256){
      const int p = tid, o = p & 127;
      float sA = sum16(s1((wg+1)&3, p), s1((wg+2)&3, p), seq);
      while (vT1[p] != seq) {}
      float tot = sA + __uint_as_float(vV1[p]) + b2n0f[o] + ro;
      if (p < 128) h1q[o] = tot; else h1k[o] = tot;
    } else {
      const int p = tid - 256;
      float sP = sum16(s1((wg+3)&3, p), s1(wg, p), seq);
      vV1[p] = __float_as_uint(sP);
      vT1[p] = seq;
    }
    __syncthreads();                       // S5: h1q/h1k ready
    // layer1 u
    float aq2[4]={0,0,0,0}, ak2[4]={0,0,0,0};
    #pragma unroll
    for (int ii=0;ii<4;ii++){
      float qi = h1q[i0+ii], ki = h1k[i0+ii];
      h1k_r[ii] = ki;
      #pragma unroll
      for (int jj=0;jj<4;jj++){
        float w = nw1[1][jj*4+ii];
        aq2[jj] = fmaf(qi, w, aq2[jj]);
        ak2[jj] = fmaf(ki, w, ak2[jj]);
      }
    }
    #pragma unroll
    for (int jj=0;jj<4;jj++){
      aq2[jj] = red32(aq2[jj]);
      ak2[jj] = red32(ak2[jj]);
    }
    float sq2q[4];
    #pragma unroll
    for (int jj=0;jj<4;jj++){
      float bb = b1n[1][j0+jj];
      float vq = aq2[jj]+bb, vk = ak2[jj]+bb;
      u2_r[jj]=vk;
      float sgk = sigm(vk);
      sg2_r[jj]=sgk; s2_r[jj]=vk*sgk;
      sq2q[jj]=vq*sigm(vq);
    }
    // layer1 out partials
    #pragma unroll
    for (int oo=0;oo<4;oo++){ oq[oo]=0.f; ok[oo]=0.f; }
    #pragma unroll
    for (int jj=0;jj<4;jj++){
      #pragma unroll
      for (int oo=0;oo<4;oo++){
        float w = nw2[1][jj*4+oo];
        oq[oo] = fmaf(sq2q[jj], w, oq[oo]);
        ok[oo] = fmaf(s2_r[jj], w, ok[oo]);
      }
    }
    #pragma unroll
    for (int oo=0;oo<4;oo++){
      oq[oo] += __shfl_xor(oq[oo], 32, 64);
      ok[oo] += __shfl_xor(ok[oo], 32, 64);
    }
    // PUBLISH type2 per-wave
    if (!(tid & 32)){
      #pragma unroll
      for (int oo=0;oo<4;oo++){
        pub(s2(wg, i0+oo)     + wv, seq, oq[oo]);
        pub(s2(wg, 128+i0+oo) + wv, seq, ok[oo]);
      }
    }
    // CONSUME type2: q primary (out), k primary (h2k), pairs via pc2
    if (tid < 128){
      const int o = tid;
      float sA = sum16(s2((wg+1)&3, o), s2((wg+2)&3, o), seq);
      while (vT2[o] != seq) {}
      float tot = h1q[o] + sA + __uint_as_float(vV2[o]) + b2n1f[o];
      if (writeOut && (o>>5)==wg)
        out[((size_t)(b*SEQ + t))*HD + o] = tot;
    } else if (tid < 256){
      const int o = tid-128, p = tid;
      float sA = sum16(s2((wg+1)&3, p), s2((wg+2)&3, p), seq);
      while (vT2[p] != seq) {}
      h2k[o] = h1k[o] + sA + __uint_as_float(vV2[p]) + b2n1f[o];
    } else {
      const int p = tid - 256;
      float sP = sum16(s2((wg+3)&3, p), s2(wg, p), seq);
      vV2[p] = __float_as_uint(sP);
      vT2[p] = seq;
    }
    // loop-top barrier (S1) makes h2k visible to the next bwd
  };

  // ---- prologue: forward k_0 with n_{-1} = p0 + m0 ----
  {
    #pragma unroll
    for (int ii=0;ii<4;ii++){
      kprev4[ii] = kbuf[((size_t)b*SEQ + 0)*HD + i0+ii];
      v_r[ii]    = vbuf[((size_t)b*SEQ + 0)*HD + i0+ii];
    }
    if (tid < HD) vc_r = vbuf[((size_t)b*SEQ + 0)*HD + tid];
    float ro0 = 0.f;
    if (tid >= 128 && tid < 256)
      ro0 = kbuf[((size_t)b*SEQ + 0)*HD + (tid-128)];
    __syncthreads();   // init (LDS p0/biases/pc tags) visible
    float ak0[4]={0,0,0,0};
    #pragma unroll
    for (int ii=0;ii<4;ii++){
      float ki = kprev4[ii];
      #pragma unroll
      for (int jj=0;jj<4;jj++)
        ak0[jj] = fmaf(ki, nw1[0][jj*4+ii], ak0[jj]);
    }
    #pragma unroll
    for (int jj=0;jj<4;jj++) ak0[jj] = red32(ak0[jj]);
    float uq0[4], uk0[4];
    #pragma unroll
    for (int jj=0;jj<4;jj++){
      float bb = b1n[0][j0+jj];
      uq0[jj] = bb;              // q-path dummy (finite, discarded)
      uk0[jj] = ak0[jj] + bb;
    }
    fwd(0, false, 1u, uq0, uk0, ro0);
  }

  float dPrev = 1.f;
  for (int t=0; t<SEQ; ++t){
    const int tn = (t < SEQ-1) ? t+1 : SEQ-1;
    __syncthreads();                       // S1: h2k from prev fwd visible
    // early loads
    float qv4[4], kv4[4];
    #pragma unroll
    for (int ii=0;ii<4;ii++){
      qv4[ii] = qbuf[((size_t)b*SEQ + t )*HD + i0+ii];
      kv4[ii] = kbuf[((size_t)b*SEQ + tn)*HD + i0+ii];
    }
    float ro = 0.f;
    if (tid < 128)      ro = qbuf[((size_t)b*SEQ + t )*HD + tid];
    else if (tid < 256) ro = kbuf[((size_t)b*SEQ + tn)*HD + (tid-128)];
    const float th = thb[b*SEQ+t];
    const float al = alb[b*SEQ+t];
    const float et = etb[b*SEQ+t];
    const float nth = -th;
    const float dcur = 1.f - al;
    const float cP = dcur - et*dPrev;
    // g2v, gu2 (weights n_{t-1})
    float g2v_r[4];
    #pragma unroll
    for (int ii=0;ii<4;ii++) g2v_r[ii] = 0.015625f*(h2k[i0+ii] - v_r[ii]);
    float acc[4]={0,0,0,0};
    #pragma unroll
    for (int oo=0;oo<4;oo++){
      float go = g2v_r[oo];
      #pragma unroll
      for (int jj=0;jj<4;jj++)
        acc[jj] = fmaf(go, nw2[1][jj*4+oo], acc[jj]);
    }
    #pragma unroll
    for (int jj=0;jj<4;jj++) acc[jj] = red32(acc[jj]);
    float gu2r[4];
    #pragma unroll
    for (int jj=0;jj<4;jj++){
      float u=u2_r[jj]; float sg=sg2_r[jj];
      gu2r[jj] = acc[jj]*sg*fmaf(u, 1.f-sg, 1.f);
    }
    // gh1 partials
    float a2[4]={0,0,0,0};
    #pragma unroll
    for (int jj=0;jj<4;jj++){
      float gj = gu2r[jj];
      #pragma unroll
      for (int ii=0;ii<4;ii++)
        a2[ii] = fmaf(gj, nw1[1][jj*4+ii], a2[ii]);
    }
    #pragma unroll
    for (int ii=0;ii<4;ii++) a2[ii] += __shfl_xor(a2[ii], 32, 64);
    const unsigned seqB = (unsigned)(t+1);
    // PUBLISH B per-wave (immediately after shfl)
    if (!(tid & 32)){
      #pragma unroll
      for (int ii=0;ii<4;ii++)
        pub(sB(wg, i0+ii) + wv, seqB, a2[ii]);
    }
    float g2vc = 0.f;
    if (tid < 128) g2vc = 0.015625f*(h2k[tid] - vc_r);
    // ---- B shadow: L1 n-updates + biases + v prefetch ----
    {
      float tg2[4], tv2[4];
      #pragma unroll
      for (int jj=0;jj<4;jj++) tg2[jj] = nth*gu2r[jj];
      #pragma unroll
      for (int ii=0;ii<4;ii++) tv2[ii] = nth*g2v_r[ii];
      #pragma unroll
      for (int jj=0;jj<4;jj++){
        float g2jt = tg2[jj], s2j = s2_r[jj];
        #pragma unroll
        for (int ii=0;ii<4;ii++){
          int e = jj*4+ii;
          nw1[1][e] = fmaf(et, nw1[1][e],
                           fmaf(cP, pw1L[1][e][tid], h1k_r[ii]*g2jt));
          nw2[1][e] = fmaf(et, nw2[1][e],
                           fmaf(cP, pw2L[1][e][tid], s2j*tv2[ii]));
        }
      }
      if (iG==0){
        #pragma unroll
        for (int jj=0;jj<4;jj++)
          b1n[1][j0+jj] = fmaf(et, b1n[1][j0+jj],
                               fmaf(cP, b1p[1][j0+jj], tg2[jj]));
      }
      if (tid < 128)
        b2n1f[tid] = fmaf(et, b2n1f[tid], fmaf(cP, b2p1f[tid], nth*g2vc));
    }
    // prefetch v_{t+1}
    #pragma unroll
    for (int ii=0;ii<4;ii++)
      v_r[ii] = vbuf[((size_t)b*SEQ + tn)*HD + i0+ii];
    if (tid < HD) vc_r = vbuf[((size_t)b*SEQ + tn)*HD + tid];
    // CONSUME B via pairs
    if (tid < 128){
      float sA = sum16(sB((wg+1)&3, tid), sB((wg+2)&3, tid), seqB);
      while (vTB[tid] != seqB) {}
      float tot = g2vc + sA + __uint_as_float(vVB[tid]);
      gh1[tid] = tot;
      b2n0f[tid] = fmaf(et, b2n0f[tid], fmaf(cP, b2p0f[tid], nth*tot));
    } else if (tid < 256){
      const int p = tid - 128;
      float sP = sum16(sB((wg+3)&3, p), sB(wg, p), seqB);
      vVB[p] = __float_as_uint(sP);
      vTB[p] = seqB;
    }
    __syncthreads();                       // S3: gh1 + biases ready
    // gu1
    float gh1_r[4];
    #pragma unroll
    for (int ii=0;ii<4;ii++) gh1_r[ii] = gh1[i0+ii];
    #pragma unroll
    for (int jj=0;jj<4;jj++) acc[jj]=0.f;
    #pragma unroll
    for (int oo=0;oo<4;oo++){
      float go = gh1_r[oo];
      #pragma unroll
      for (int jj=0;jj<4;jj++)
        acc[jj] = fmaf(go, nw2[0][jj*4+oo], acc[jj]);
    }
    #pragma unroll
    for (int jj=0;jj<4;jj++) acc[jj] = red32(acc[jj]);
    float gu1r[4];
    #pragma unroll
    for (int jj=0;jj<4;jj++){
      float u=u1_r[jj]; float sg=sg1_r[jj];
      gu1r[jj] = acc[jj]*sg*fmaf(u, 1.f-sg, 1.f);
    }
    // layer-0 n-updates
    {
      float tg1[4], tv0[4];
      #pragma unroll
      for (int jj=0;jj<4;jj++) tg1[jj] = nth*gu1r[jj];
      #pragma unroll
      for (int ii=0;ii<4;ii++) tv0[ii] = nth*gh1_r[ii];
      #pragma unroll
      for (int jj=0;jj<4;jj++){
        float g1jt = tg1[jj], s1j = s1_r[jj];
        #pragma unroll
        for (int ii=0;ii<4;ii++){
          int e = jj*4+ii;
          nw1[0][e] = fmaf(et, nw1[0][e],
                           fmaf(cP, pw1L[0][e][tid], kprev4[ii]*g1jt));
          nw2[0][e] = fmaf(et, nw2[0][e],
                           fmaf(cP, pw2L[0][e][tid], s1j*tv0[ii]));
        }
      }
      if (iG==0){
        #pragma unroll
        for (int jj=0;jj<4;jj++)
          b1n[0][j0+jj] = fmaf(et, b1n[0][j0+jj],
                               fmaf(cP, b1p[0][j0+jj], tg1[jj]));
      }
    }
    // layer-0 dual u with n_t
    float aq[4]={0,0,0,0}, ak[4]={0,0,0,0};
    #pragma unroll
    for (int ii=0;ii<4;ii++){
      float qi = qv4[ii], ki = kv4[ii];
      #pragma unroll
      for (int jj=0;jj<4;jj++){
        float w = nw1[0][jj*4+ii];
        aq[jj] = fmaf(qi, w, aq[jj]);
        ak[jj] = fmaf(ki, w, ak[jj]);
      }
    }
    #pragma unroll
    for (int jj=0;jj<4;jj++){
      aq[jj] = red32(aq[jj]);
      ak[jj] = red32(ak[jj]);
    }
    float uqf[4], ukf[4];
    #pragma unroll
    for (int jj=0;jj<4;jj++){
      float bb = b1n[0][j0+jj];   // wave-local RAW (writer iG==0 same wave)
      uqf[jj] = aq[jj] + bb;
      ukf[jj] = ak[jj] + bb;
    }
    #pragma unroll
    for (int ii=0;ii<4;ii++) kprev4[ii] = kv4[ii];
    dPrev = dcur;
    fwd(t, true, (unsigned)(t+2), uqf, ukf, ro);
  }
}

extern "C" void kernel_launch(void* const* d_in, const int* in_sizes, int n_in,
                              void* d_out, int out_size, void* d_ws, size_t ws_size,
                              hipStream_t stream)
{
  (void)in_sizes; (void)n_in; (void)out_size; (void)ws_size;
  const float* x    = (const float*)d_in[0];
  const float* Wq   = (const float*)d_in[1];
  const float* Wk   = (const float*)d_in[2];
  const float* Wv   = (const float*)d_in[3];
  const float* w_lr = (const float*)d_in[4];
  const float* b_lr = (const float*)d_in[5];
  const float* w_fg = (const float*)d_in[6];
  const float* b_fg = (const float*)d_in[7];
  const float* w_mo = (const float*)d_in[8];
  const float* b_mo = (const float*)d_in[9];
  const float* w1_0 = (const float*)d_in[10];
  const float* b1_0 = (const float*)d_in[11];
  const float* w2_0 = (const float*)d_in[12];
  const float* b2_0 = (const float*)d_in[13];
  const float* m_w1_0 = (const float*)d_in[14];
  const float* m_b1_0 = (const float*)d_in[15];
  const float* m_w2_0 = (const float*)d_in[16];
  const float* m_b2_0 = (const float*)d_in[17];
  const float* w1_1 = (const float*)d_in[18];
  const float* b1_1 = (const float*)d_in[19];
  const float* w2_1 = (const float*)d_in[20];
  const float* b2_1 = (const float*)d_in[21];
  const float* m_w1_1 = (const float*)d_in[22];
  const float* m_b1_1 = (const float*)d_in[23];
  const float* m_w2_1 = (const float*)d_in[24];
  const float* m_b2_1 = (const float*)d_in[25];

  float* wsf = (float*)d_ws;
  ull* red = (ull*)d_ws;                 // 4 batches x 20480 ull = 640 KB
  float* qbuf = wsf + 163840;            // after slot region
  float* kbuf = qbuf + NB*SEQ*HD;
  float* vbuf = kbuf + NB*SEQ*HD;
  float* thb  = vbuf + NB*SEQ*HD;
  float* alb  = thb + NB*SEQ;
  float* etb  = alb + NB*SEQ;
  // ws re-poisoned to 0xAA each launch; 0xAAAAAAAA is never a valid seq tag.

  qkv_kernel<<<dim3(NB*SEQ/TOK), dim3(HD), 0, stream>>>(
      x, Wq, Wk, Wv, w_lr, b_lr, w_fg, b_fg, w_mo, b_mo,
      qbuf, kbuf, vbuf, thb, alb, etb);

  // 32 blocks: 16 active (4 batches x 4 WGs, co-located per XCD), 16 exit.
  scan_kernel<<<dim3(4*NWG*2), dim3(512), 0, stream>>>(
      w1_0, b1_0, w2_0, b2_0, m_w1_0, m_b1_0, m_w2_0, m_b2_0,
      w1_1, b1_1, w2_1, b2_1, m_w1_1, m_b1_1, m_w2_1, m_b2_1,
      qbuf, kbuf, vbuf, thb, alb, etb,
      red, (float*)d_out);
}

// Round 11
// 1785.624 us; speedup vs baseline: 3.7653x; 3.7653x over previous
//
#include <hip/hip_runtime.h>

// NeuralMemory scan: B=4, S=256, H=128, EXP=2, DEPTH=2.
// Round 21: REVERT to R17 verbatim (verified: bench 1786us, scan 1645us,
// absmax 4.768e-7). Falsification ledger for the poll-RT attack:
//  - R18 consumer sc0 loads: sc1 publish stores do NOT refresh the local
//    L2 -> stale-clean lines, +690us.
//  - R19 no-sc1 atomic publish: still executes at the memory-side
//    coherence point (WRITE_SIZE 2x), +680us.
//  - R20 per-wave publish (8x slots, consumer-side combine): IF$ traffic
//    explosion (WRITE 662MB, FETCH 221MB), 4-16x regression.
// Structure: column-split WGs + DEPTH=2 need exactly 3 all-to-all
// exchanges/step (one per silu boundary + one bwd); linearity only moves
// exchanges. Replication (R11/12) can't get VGPRs; q-deferral (R13)
// lengthens the pollers' path. Step budget 6.4us = 3xRT(IF$) ~3.6 +
// VALU ~2.0 + barriers ~0.8 -> within ~15% of the partition's floor.
// This kernel: R16 (DPP reduces + fast sigmoid + 8-tok qkv) + XCD
// co-location (32 blocks, XCD=bid%8, batch b on XCD b).

constexpr int HD  = 128;   // H
constexpr int SEQ = 256;   // S
constexpr int NB  = 4;     // B
constexpr int ED  = 256;   // H*EXP
constexpr int CW  = 64;    // hidden units per WG per layer (ED/NWG)
constexpr int NWG = 4;     // workgroups per batch
constexpr int TOK = 8;     // tokens per qkv block

// fast sigmoid: v_exp_f32 computes 2^x, so 1/(1+e^-x) = rcp(1 + 2^(-x*log2e)).
__device__ __forceinline__ float sigm(float x){
  float e;
  asm("v_exp_f32 %0, %1" : "=v"(e) : "v"(x * -1.44269504088896f));
  float r;
  asm("v_rcp_f32 %0, %1" : "=v"(r) : "v"(1.0f + e));
  return r;
}

// DPP-add helper: x + perm(x); ctrl must be a compile-time constant.
template<int CTRL>
__device__ __forceinline__ float dpp_add(float x){
  int y = __builtin_amdgcn_update_dpp(0, __float_as_int(x), CTRL, 0xF, 0xF, true);
  return x + __int_as_float(y);
}
// sum over each 32-lane group (bits 0..4), result in all lanes.
__device__ __forceinline__ float red32(float x){
  x = dpp_add<0xB1>(x);
  x = dpp_add<0x4E>(x);
  x = dpp_add<0x141>(x);
  x = dpp_add<0x140>(x);
  x += __int_as_float(__builtin_amdgcn_ds_swizzle(__float_as_int(x), 0x401F));
  return x;
}
__device__ __forceinline__ float red64(float x){
  x = red32(x);
  x += __shfl_xor(x, 32, 64);
  return x;
}

// ---------------- kernel 1: q/k/v + gate scalars (8 tokens/block) ----------------
__global__ __launch_bounds__(128) void qkv_kernel(
    const float* __restrict__ x,
    const float* __restrict__ Wq, const float* __restrict__ Wk, const float* __restrict__ Wv,
    const float* __restrict__ w_lr, const float* __restrict__ b_lr,
    const float* __restrict__ w_fg, const float* __restrict__ b_fg,
    const float* __restrict__ w_mo, const float* __restrict__ b_mo,
    float* __restrict__ qb, float* __restrict__ kb, float* __restrict__ vb,
    float* __restrict__ thb, float* __restrict__ alb, float* __restrict__ etb)
{
  const int t0 = blockIdx.x * TOK;    // first flattened token (b*SEQ+s)
  const int o  = threadIdx.x;         // 0..127
  __shared__ float xl[TOK][HD];
  __shared__ float red2[2][8];        // cross-wave partials

  #pragma unroll
  for (int tt=0; tt<TOK; ++tt)
    xl[tt][o] = x[(size_t)(t0+tt)*HD + o];
  const float wl = w_lr[o], wf = w_fg[o], wm = w_mo[o];
  const float blr = b_lr[0], bfg = b_fg[0], bmo = b_mo[0];
  __syncthreads();

  float aq[TOK], ak[TOK], av[TOK];
  #pragma unroll
  for (int tt=0; tt<TOK; ++tt){ aq[tt]=0.f; ak[tt]=0.f; av[tt]=0.f; }
  for (int i=0; i<HD; i+=4){
    float wq0=Wq[(i+0)*HD+o], wk0=Wk[(i+0)*HD+o], wv0=Wv[(i+0)*HD+o];
    float wq1=Wq[(i+1)*HD+o], wk1=Wk[(i+1)*HD+o], wv1=Wv[(i+1)*HD+o];
    float wq2=Wq[(i+2)*HD+o], wk2=Wk[(i+2)*HD+o], wv2=Wv[(i+2)*HD+o];
    float wq3=Wq[(i+3)*HD+o], wk3=Wk[(i+3)*HD+o], wv3=Wv[(i+3)*HD+o];
    #pragma unroll
    for (int tt=0; tt<TOK; ++tt){
      float4 xv = *reinterpret_cast<const float4*>(&xl[tt][i]);
      aq[tt]=fmaf(xv.x,wq0,aq[tt]); ak[tt]=fmaf(xv.x,wk0,ak[tt]); av[tt]=fmaf(xv.x,wv0,av[tt]);
      aq[tt]=fmaf(xv.y,wq1,aq[tt]); ak[tt]=fmaf(xv.y,wk1,ak[tt]); av[tt]=fmaf(xv.y,wv1,av[tt]);
      aq[tt]=fmaf(xv.z,wq2,aq[tt]); ak[tt]=fmaf(xv.z,wk2,ak[tt]); av[tt]=fmaf(xv.z,wv2,av[tt]);
      aq[tt]=fmaf(xv.w,wq3,aq[tt]); ak[tt]=fmaf(xv.w,wk3,ak[tt]); av[tt]=fmaf(xv.w,wv3,av[tt]);
    }
  }
  #pragma unroll
  for (int tt=0; tt<TOK; ++tt){
    const size_t idx = (size_t)(t0+tt);
    float a_q=aq[tt], a_k=ak[tt], a_v=av[tt];
    float sq_ = a_q*sigm(a_q);
    float sk_ = a_k*sigm(a_k);
    float sv_ = a_v*sigm(a_v);
    float xo = xl[tt][o];
    float p0 = red64(sq_*sq_);
    float p1 = red64(sk_*sk_);
    float p2 = red64(xo*wl);
    float p3 = red64(xo*wf);
    float p4 = red64(xo*wm);
    if ((o&63)==0){
      int w = o>>6;
      red2[w][0]=p0; red2[w][1]=p1; red2[w][2]=p2; red2[w][3]=p3; red2[w][4]=p4;
    }
    __syncthreads();
    float nq = red2[0][0]+red2[1][0];
    float nk = red2[0][1]+red2[1][1];
    qb[idx*HD+o] = sq_ / fmaxf(sqrtf(nq), 1e-12f);
    kb[idx*HD+o] = sk_ / fmaxf(sqrtf(nk), 1e-12f);
    vb[idx*HD+o] = sv_;
    if (o==0){
      float dl = red2[0][2]+red2[1][2];
      float df = red2[0][3]+red2[1][3];
      float dm = red2[0][4]+red2[1][4];
      thb[idx] = sigm(dl + blr) * 0.01f;   // MAX_LR
      alb[idx] = sigm(df + bfg);
      etb[idx] = sigm(dm + bmo);
    }
    __syncthreads();   // red2 reuse next token
  }
}

// ---------------- kernel 2: the sequential scan ----------------
__global__ __launch_bounds__(512, 1) void scan_kernel(
    const float* __restrict__ w1_0g, const float* __restrict__ b1_0g,
    const float* __restrict__ w2_0g, const float* __restrict__ b2_0g,
    const float* __restrict__ mw1_0g, const float* __restrict__ mb1_0g,
    const float* __restrict__ mw2_0g, const float* __restrict__ mb2_0g,
    const float* __restrict__ w1_1g, const float* __restrict__ b1_1g,
    const float* __restrict__ w2_1g, const float* __restrict__ b2_1g,
    const float* __restrict__ mw1_1g, const float* __restrict__ mb1_1g,
    const float* __restrict__ mw2_1g, const float* __restrict__ mb2_1g,
    const float* __restrict__ qbuf, const float* __restrict__ kbuf, const float* __restrict__ vbuf,
    const float* __restrict__ thb, const float* __restrict__ alb, const float* __restrict__ etb,
    unsigned long long* __restrict__ red, float* __restrict__ out)
{
  // XCD co-location: de-facto mapping is XCD = blockIdx % 8. Launch 32
  // blocks; keep only (rb&7) < NB. Batch b's 4 WGs are bids {b,b+8,b+16,
  // b+24} -> all on XCD b -> poll slots stay in that XCD's L2.
  const int rb  = blockIdx.x;
  const int b   = rb & 7;      // candidate batch = XCD id
  if (b >= NB) return;         // XCDs 4..7: no work
  const int wg  = rb >> 3;     // 0..3 within batch
  const int tid = threadIdx.x;
  const int iG  = tid & 31;    // i-group (w1) / o-group (w2)
  const int jG  = tid >> 5;    // j-group 0..15
  const int i0  = iG*4;
  const int j0  = jG*4;
  const int c0  = wg*CW;

  __shared__ float pw1L[2][16][512];   // 64 KB p0 (w1), [plane][tid]
  __shared__ float pw2L[2][16][512];   // 64 KB p0 (w2)
  __shared__ float h1k[HD], h1q[HD], h2k[HD], gh1[HD];
  __shared__ float redbuf[8][256];
  __shared__ float b1p[2][CW], b1n[2][CW], b2p[2][32], b2n[2][32];

  // actual weights n = p0*(1-a) + m, carried in registers
  float nw1[2][16], nw2[2][16];
  {
    const float* w1s[2]  = {w1_0g,  w1_1g};
    const float* mw1s[2] = {mw1_0g, mw1_1g};
    const float* w2s[2]  = {w2_0g,  w2_1g};
    const float* mw2s[2] = {mw2_0g, mw2_1g};
    #pragma unroll
    for (int l=0;l<2;l++){
      #pragma unroll
      for (int jj=0;jj<4;jj++){
        #pragma unroll
        for (int ii=0;ii<4;ii++){
          int gi1 = (i0+ii)*ED + (c0+j0+jj);
          float p1 = w1s[l][gi1];
          pw1L[l][jj*4+ii][tid] = p1;
          nw1[l][jj*4+ii] = p1 + mw1s[l][gi1];   // n_{-1} = p0 + m0
          int gi2 = (c0+j0+jj)*HD + (i0+ii);
          float p2 = w2s[l][gi2];
          pw2L[l][jj*4+ii][tid] = p2;
          nw2[l][jj*4+ii] = p2 + mw2s[l][gi2];
        }
      }
    }
  }
  if (tid < CW){
    float p0a = b1_0g[c0+tid], p1a = b1_1g[c0+tid];
    b1p[0][tid] = p0a; b1n[0][tid] = p0a + mb1_0g[c0+tid];
    b1p[1][tid] = p1a; b1n[1][tid] = p1a + mb1_1g[c0+tid];
  } else if (tid < CW+32){
    int oo = tid - CW;
    float p0a = b2_0g[wg*32+oo], p1a = b2_1g[wg*32+oo];
    b2p[0][oo] = p0a; b2n[0][oo] = p0a + mb2_0g[wg*32+oo];
    b2p[1][oo] = p1a; b2n[1][oo] = p1a + mb2_1g[wg*32+oo];
  }

  auto pubstore = [&](int type, unsigned seq, int idx, float val){
    unsigned long long* p = red + (((b*3+type)*NWG + wg)*256 + idx);
    unsigned long long pk = ((unsigned long long)seq << 32) |
                            (unsigned long long)__float_as_uint(val);
    __hip_atomic_store(p, pk, __ATOMIC_RELAXED, __HIP_MEMORY_SCOPE_AGENT);
  };
  auto pollacc = [&](int type, unsigned seq, int idx, float own)->float{
    unsigned long long* base = red + ((b*3+type)*NWG)*256;
    const int wA=((wg+1)&3)*256+idx, wB=((wg+2)&3)*256+idx, wC=((wg+3)&3)*256+idx;
    unsigned long long vA = __hip_atomic_load(base+wA, __ATOMIC_RELAXED, __HIP_MEMORY_SCOPE_AGENT);
    unsigned long long vB = __hip_atomic_load(base+wB, __ATOMIC_RELAXED, __HIP_MEMORY_SCOPE_AGENT);
    unsigned long long vC = __hip_atomic_load(base+wC, __ATOMIC_RELAXED, __HIP_MEMORY_SCOPE_AGENT);
    float s = own; unsigned got = 0;
    while (got != 7u){
      if (!(got&1u)){
        if ((unsigned)(vA>>32)==seq){ s += __uint_as_float((unsigned)vA); got|=1u; }
        else vA = __hip_atomic_load(base+wA, __ATOMIC_RELAXED, __HIP_MEMORY_SCOPE_AGENT);
      }
      if (!(got&2u)){
        if ((unsigned)(vB>>32)==seq){ s += __uint_as_float((unsigned)vB); got|=2u; }
        else vB = __hip_atomic_load(base+wB, __ATOMIC_RELAXED, __HIP_MEMORY_SCOPE_AGENT);
      }
      if (!(got&4u)){
        if ((unsigned)(vC>>32)==seq){ s += __uint_as_float((unsigned)vC); got|=4u; }
        else vC = __hip_atomic_load(base+wC, __ATOMIC_RELAXED, __HIP_MEMORY_SCOPE_AGENT);
      }
    }
    return s;
  };

  // loop-carried per-thread state
  float u1_r[4], s1_r[4], sg1_r[4], u2_r[4], s2_r[4], sg2_r[4], h1k_r[4], v_r[4], vc_r = 0.f;
  float kprev4[4];   // k_t (this step's grad key), i0-range

  // forward from biased layer-0 pre-activations uq/uk.
  // ro = F1 residual (tid<128: q_t[tid]; 128..255: k_{t+1}[tid-128]).
  auto fwdFromU = [&](int t, bool writeOut, unsigned seq,
                      const float* uq, const float* uk, float ro){
    float sq1q[4];
    #pragma unroll
    for (int jj=0;jj<4;jj++){
      float vq = uq[jj], vk = uk[jj];
      u1_r[jj]=vk;
      float sgk = sigm(vk);
      sg1_r[jj]=sgk; s1_r[jj]=vk*sgk;
      sq1q[jj]=vq*sigm(vq);
    }
    // ---- layer0 out partials (nw2[0] = n_t, updated before call) ----
    float oq[4]={0,0,0,0}, ok[4]={0,0,0,0};
    #pragma unroll
    for (int jj=0;jj<4;jj++){
      #pragma unroll
      for (int oo=0;oo<4;oo++){
        float w = nw2[0][jj*4+oo];
        oq[oo] = fmaf(sq1q[jj], w, oq[oo]);
        ok[oo] = fmaf(s1_r[jj], w, ok[oo]);
      }
    }
    #pragma unroll
    for (int oo=0;oo<4;oo++){
      oq[oo] += __shfl_xor(oq[oo], 32, 64);
      ok[oo] += __shfl_xor(ok[oo], 32, 64);
    }
    if (!(tid & 32)){
      int wv = tid>>6;
      #pragma unroll
      for (int oo=0;oo<4;oo++){
        redbuf[wv][i0+oo]     = oq[oo];
        redbuf[wv][128+i0+oo] = ok[oo];
      }
    }
    __syncthreads();                       // S4
    if (tid < 256){
      float p=0.f;
      #pragma unroll
      for (int w_=0; w_<8; w_++) p += redbuf[w_][tid];
      int o = tid & 127;
      if (o >= wg*32 && o < wg*32+32)
        p += b2n[0][o-wg*32];
      pubstore(1, seq, tid, p);
      float s0 = ro + pollacc(1, seq, tid, p);
      if (tid<128) h1q[o]=s0; else h1k[o]=s0;
    }
    __syncthreads();                       // S5
    // ---- layer1 u ----
    float aq2[4]={0,0,0,0}, ak2[4]={0,0,0,0};
    #pragma unroll
    for (int ii=0;ii<4;ii++){
      float qi = h1q[i0+ii], ki = h1k[i0+ii];
      h1k_r[ii] = ki;
      #pragma unroll
      for (int jj=0;jj<4;jj++){
        float w = nw1[1][jj*4+ii];
        aq2[jj] = fmaf(qi, w, aq2[jj]);
        ak2[jj] = fmaf(ki, w, ak2[jj]);
      }
    }
    #pragma unroll
    for (int jj=0;jj<4;jj++){
      aq2[jj] = red32(aq2[jj]);
      ak2[jj] = red32(ak2[jj]);
    }
    float sq2q[4];
    #pragma unroll
    for (int jj=0;jj<4;jj++){
      float bb = b1n[1][j0+jj];
      float vq = aq2[jj]+bb, vk = ak2[jj]+bb;
      u2_r[jj]=vk;
      float sgk = sigm(vk);
      sg2_r[jj]=sgk; s2_r[jj]=vk*sgk;
      sq2q[jj]=vq*sigm(vq);
    }
    // ---- layer1 out partials ----
    #pragma unroll
    for (int oo=0;oo<4;oo++){ oq[oo]=0.f; ok[oo]=0.f; }
    #pragma unroll
    for (int jj=0;jj<4;jj++){
      #pragma unroll
      for (int oo=0;oo<4;oo++){
        float w = nw2[1][jj*4+oo];
        oq[oo] = fmaf(sq2q[jj], w, oq[oo]);
        ok[oo] = fmaf(s2_r[jj], w, ok[oo]);
      }
    }
    #pragma unroll
    for (int oo=0;oo<4;oo++){
      oq[oo] += __shfl_xor(oq[oo], 32, 64);
      ok[oo] += __shfl_xor(ok[oo], 32, 64);
    }
    if (!(tid & 32)){
      int wv = tid>>6;
      #pragma unroll
      for (int oo=0;oo<4;oo++){
        redbuf[wv][i0+oo]     = oq[oo];
        redbuf[wv][128+i0+oo] = ok[oo];
      }
    }
    __syncthreads();                       // S6
    if (tid < 256){
      float p=0.f;
      #pragma unroll
      for (int w_=0; w_<8; w_++) p += redbuf[w_][tid];
      int o = tid & 127;
      if (o >= wg*32 && o < wg*32+32)
        p += b2n[1][o-wg*32];
      pubstore(2, seq, tid, p);
      float s0 = ((tid<128) ? h1q[o] : h1k[o]) + pollacc(2, seq, tid, p);
      if (tid<128){
        if (writeOut && o >= wg*32 && o < wg*32+32)
          out[((size_t)(b*SEQ + t))*HD + o] = s0;
      } else {
        h2k[o] = s0;
      }
    }
  };

  // ---- prologue: forward k_0 with n_{-1} = p0 + m0 (m0=0 pristine) ----
  {
    #pragma unroll
    for (int ii=0;ii<4;ii++){
      kprev4[ii] = kbuf[((size_t)b*SEQ + 0)*HD + i0+ii];
      v_r[ii]    = vbuf[((size_t)b*SEQ + 0)*HD + i0+ii];
    }
    if (tid < HD) vc_r = vbuf[((size_t)b*SEQ + 0)*HD + tid];
    float ro0 = 0.f;
    if (tid >= 128 && tid < 256)
      ro0 = kbuf[((size_t)b*SEQ + 0)*HD + (tid-128)];
    __syncthreads();   // init (LDS p0/biases) visible
    float ak0[4]={0,0,0,0};
    #pragma unroll
    for (int ii=0;ii<4;ii++){
      float ki = kprev4[ii];
      #pragma unroll
      for (int jj=0;jj<4;jj++)
        ak0[jj] = fmaf(ki, nw1[0][jj*4+ii], ak0[jj]);
    }
    #pragma unroll
    for (int jj=0;jj<4;jj++) ak0[jj] = red32(ak0[jj]);
    float uq0[4], uk0[4];
    #pragma unroll
    for (int jj=0;jj<4;jj++){
      float bb = b1n[0][j0+jj];
      uq0[jj] = bb;              // q-path = 0 vector (discarded)
      uk0[jj] = ak0[jj] + bb;
    }
    fwdFromU(0, false, 1u, uq0, uk0, ro0);
  }

  float dPrev = 1.f;   // 1 - alpha_{-1}
  for (int t=0; t<SEQ; ++t){
    const int tn = (t < SEQ-1) ? t+1 : SEQ-1;
    // ---- early global loads: q_t, k_{t+1} (hidden under S1 + backward) ----
    float qv4[4], kv4[4];
    #pragma unroll
    for (int ii=0;ii<4;ii++){
      qv4[ii] = qbuf[((size_t)b*SEQ + t )*HD + i0+ii];
      kv4[ii] = kbuf[((size_t)b*SEQ + tn)*HD + i0+ii];
    }
    float ro = 0.f;
    if (tid < 128)      ro = qbuf[((size_t)b*SEQ + t )*HD + tid];
    else if (tid < 256) ro = kbuf[((size_t)b*SEQ + tn)*HD + (tid-128)];
    const float th = thb[b*SEQ+t];
    const float al = alb[b*SEQ+t];
    const float et = etb[b*SEQ+t];
    const float nth = -th;
    const float dcur = 1.f - al;
    const float cP = dcur - et*dPrev;
    __syncthreads();                       // S1: h2k from prev fwd visible
    // ---- g2v, gu2 (weights n_{t-1}) ----
    float g2v_r[4];
    #pragma unroll
    for (int ii=0;ii<4;ii++) g2v_r[ii] = 0.015625f*(h2k[i0+ii] - v_r[ii]);
    float acc[4]={0,0,0,0};
    #pragma unroll
    for (int oo=0;oo<4;oo++){
      float go = g2v_r[oo];
      #pragma unroll
      for (int jj=0;jj<4;jj++)
        acc[jj] = fmaf(go, nw2[1][jj*4+oo], acc[jj]);
    }
    #pragma unroll
    for (int jj=0;jj<4;jj++) acc[jj] = red32(acc[jj]);
    float gu2r[4];
    #pragma unroll
    for (int jj=0;jj<4;jj++){
      float u=u2_r[jj]; float sg=sg2_r[jj];          // cached from fwd
      gu2r[jj] = acc[jj]*sg*fmaf(u, 1.f-sg, 1.f);
    }
    // ---- gh1 partial ----
    float a2[4]={0,0,0,0};
    #pragma unroll
    for (int jj=0;jj<4;jj++){
      float gj = gu2r[jj];
      #pragma unroll
      for (int ii=0;ii<4;ii++)
        a2[ii] = fmaf(gj, nw1[1][jj*4+ii], a2[ii]);
    }
    #pragma unroll
    for (int ii=0;ii<4;ii++) a2[ii] += __shfl_xor(a2[ii], 32, 64);
    if (!(tid & 32)){
      int wv = tid>>6;
      #pragma unroll
      for (int ii=0;ii<4;ii++) redbuf[wv][i0+ii] = a2[ii];
    }
    __syncthreads();                       // S2
    const unsigned seqB = (unsigned)(t+1);
    float pB = 0.f, g2vc = 0.f;
    if (tid < HD){
      #pragma unroll
      for (int w_=0;w_<8;w_++) pB += redbuf[w_][tid];
      pubstore(0, seqB, tid, pB);          // publish ASAP
      g2vc = 0.015625f*(h2k[tid] - vc_r);
    }
    // ---- B-poll shadow: layer-1 n-updates + v prefetch ----
    {
      float tg2[4], tv2[4];
      #pragma unroll
      for (int jj=0;jj<4;jj++) tg2[jj] = nth*gu2r[jj];
      #pragma unroll
      for (int ii=0;ii<4;ii++) tv2[ii] = nth*g2v_r[ii];
      #pragma unroll
      for (int jj=0;jj<4;jj++){
        float g2jt = tg2[jj], s2j = s2_r[jj];
        #pragma unroll
        for (int ii=0;ii<4;ii++){
          int e = jj*4+ii;
          nw1[1][e] = fmaf(et, nw1[1][e],
                           fmaf(cP, pw1L[1][e][tid], h1k_r[ii]*g2jt));
          nw2[1][e] = fmaf(et, nw2[1][e],
                           fmaf(cP, pw2L[1][e][tid], s2j*tv2[ii]));
        }
      }
      if (iG==0){
        #pragma unroll
        for (int jj=0;jj<4;jj++)
          b1n[1][j0+jj] = fmaf(et, b1n[1][j0+jj],
                               fmaf(cP, b1p[1][j0+jj], tg2[jj]));
      }
      if (jG==0 && iG>=wg*8 && iG<wg*8+8){
        #pragma unroll
        for (int ii=0;ii<4;ii++)
          b2n[1][i0+ii-wg*32] = fmaf(et, b2n[1][i0+ii-wg*32],
                                     fmaf(cP, b2p[1][i0+ii-wg*32], tv2[ii]));
      }
    }
    // prefetch v_{t+1} (old v consumed above)
    #pragma unroll
    for (int ii=0;ii<4;ii++)
      v_r[ii] = vbuf[((size_t)b*SEQ + tn)*HD + i0+ii];
    if (tid < HD) vc_r = vbuf[((size_t)b*SEQ + tn)*HD + tid];
    // ---- poll B ----
    if (tid < HD)
      gh1[tid] = g2vc + pollacc(0, seqB, tid, pB);
    __syncthreads();                       // S3
    // ---- gu1 (weights nw2[0] = n_{t-1}) ----
    float gh1_r[4];
    #pragma unroll
    for (int ii=0;ii<4;ii++) gh1_r[ii] = gh1[i0+ii];
    #pragma unroll
    for (int jj=0;jj<4;jj++) acc[jj]=0.f;
    #pragma unroll
    for (int oo=0;oo<4;oo++){
      float go = gh1_r[oo];
      #pragma unroll
      for (int jj=0;jj<4;jj++)
        acc[jj] = fmaf(go, nw2[0][jj*4+oo], acc[jj]);
    }
    #pragma unroll
    for (int jj=0;jj<4;jj++) acc[jj] = red32(acc[jj]);
    float gu1r[4];
    #pragma unroll
    for (int jj=0;jj<4;jj++){
      float u=u1_r[jj]; float sg=sg1_r[jj];          // cached from fwd
      gu1r[jj] = acc[jj]*sg*fmaf(u, 1.f-sg, 1.f);
    }
    // ---- layer-0 n-updates (LDS p0 reads) ----
    {
      float tg1[4], tv0[4];
      #pragma unroll
      for (int jj=0;jj<4;jj++) tg1[jj] = nth*gu1r[jj];
      #pragma unroll
      for (int ii=0;ii<4;ii++) tv0[ii] = nth*gh1_r[ii];
      #pragma unroll
      for (int jj=0;jj<4;jj++){
        float g1jt = tg1[jj], s1j = s1_r[jj];
        #pragma unroll
        for (int ii=0;ii<4;ii++){
          int e = jj*4+ii;
          nw1[0][e] = fmaf(et, nw1[0][e],
                           fmaf(cP, pw1L[0][e][tid], kprev4[ii]*g1jt));
          nw2[0][e] = fmaf(et, nw2[0][e],
                           fmaf(cP, pw2L[0][e][tid], s1j*tv0[ii]));
        }
      }
      if (iG==0){
        #pragma unroll
        for (int jj=0;jj<4;jj++)
          b1n[0][j0+jj] = fmaf(et, b1n[0][j0+jj],
                               fmaf(cP, b1p[0][j0+jj], tg1[jj]));
      }
      if (jG==0 && iG>=wg*8 && iG<wg*8+8){
        #pragma unroll
        for (int ii=0;ii<4;ii++)
          b2n[0][i0+ii-wg*32] = fmaf(et, b2n[0][i0+ii-wg*32],
                                     fmaf(cP, b2p[0][i0+ii-wg*32], tv0[ii]));
      }
    }
    // ---- layer-0 dual u with updated n_t (register q/k inputs) ----
    float aq[4]={0,0,0,0}, ak[4]={0,0,0,0};
    #pragma unroll
    for (int ii=0;ii<4;ii++){
      float qi = qv4[ii], ki = kv4[ii];
      #pragma unroll
      for (int jj=0;jj<4;jj++){
        float w = nw1[0][jj*4+ii];
        aq[jj] = fmaf(qi, w, aq[jj]);
        ak[jj] = fmaf(ki, w, ak[jj]);
      }
    }
    #pragma unroll
    for (int jj=0;jj<4;jj++){
      aq[jj] = red32(aq[jj]);
      ak[jj] = red32(ak[jj]);
    }
    float uqf[4], ukf[4];
    #pragma unroll
    for (int jj=0;jj<4;jj++){
      float bb = b1n[0][j0+jj];   // wave-local RAW (writer iG==0 same wave)
      uqf[jj] = aq[jj] + bb;
      ukf[jj] = ak[jj] + bb;
    }
    #pragma unroll
    for (int ii=0;ii<4;ii++) kprev4[ii] = kv4[ii];   // k~ for next step
    dPrev = dcur;
    fwdFromU(t, true, (unsigned)(t+2), uqf, ukf, ro);
  }
}

extern "C" void kernel_launch(void* const* d_in, const int* in_sizes, int n_in,
                              void* d_out, int out_size, void* d_ws, size_t ws_size,
                              hipStream_t stream)
{
  (void)in_sizes; (void)n_in; (void)out_size; (void)ws_size;
  const float* x    = (const float*)d_in[0];
  const float* Wq   = (const float*)d_in[1];
  const float* Wk   = (const float*)d_in[2];
  const float* Wv   = (const float*)d_in[3];
  const float* w_lr = (const float*)d_in[4];
  const float* b_lr = (const float*)d_in[5];
  const float* w_fg = (const float*)d_in[6];
  const float* b_fg = (const float*)d_in[7];
  const float* w_mo = (const float*)d_in[8];
  const float* b_mo = (const float*)d_in[9];
  const float* w1_0 = (const float*)d_in[10];
  const float* b1_0 = (const float*)d_in[11];
  const float* w2_0 = (const float*)d_in[12];
  const float* b2_0 = (const float*)d_in[13];
  const float* m_w1_0 = (const float*)d_in[14];
  const float* m_b1_0 = (const float*)d_in[15];
  const float* m_w2_0 = (const float*)d_in[16];
  const float* m_b2_0 = (const float*)d_in[17];
  const float* w1_1 = (const float*)d_in[18];
  const float* b1_1 = (const float*)d_in[19];
  const float* w2_1 = (const float*)d_in[20];
  const float* b2_1 = (const float*)d_in[21];
  const float* m_w1_1 = (const float*)d_in[22];
  const float* m_b1_1 = (const float*)d_in[23];
  const float* m_w2_1 = (const float*)d_in[24];
  const float* m_b2_1 = (const float*)d_in[25];

  float* wsf = (float*)d_ws;
  unsigned long long* red = (unsigned long long*)d_ws;   // 98304 B of slots
  float* qbuf = wsf + 32768;
  float* kbuf = qbuf + NB*SEQ*HD;
  float* vbuf = kbuf + NB*SEQ*HD;
  float* thb  = vbuf + NB*SEQ*HD;
  float* alb  = thb + NB*SEQ;
  float* etb  = alb + NB*SEQ;
  // ws re-poisoned to 0xAA each launch; 0xAAAAAAAA is never a valid seq tag.

  qkv_kernel<<<dim3(NB*SEQ/TOK), dim3(HD), 0, stream>>>(
      x, Wq, Wk, Wv, w_lr, b_lr, w_fg, b_fg, w_mo, b_mo,
      qbuf, kbuf, vbuf, thb, alb, etb);

  // 32 blocks: 16 active (4 batches x 4 WGs, co-located per XCD), 16 exit.
  scan_kernel<<<dim3(4*NWG*2), dim3(512), 0, stream>>>(
      w1_0, b1_0, w2_0, b2_0, m_w1_0, m_b1_0, m_w2_0, m_b2_0,
      w1_1, b1_1, w2_1, b2_1, m_w1_1, m_b1_1, m_w2_1, m_b2_1,
      qbuf, kbuf, vbuf, thb, alb, etb,
      red, (float*)d_out);
}